// Round 3
// baseline (215.931 us; speedup 1.0000x reference)
//
#include <hip/hip_runtime.h>
#include <hip/hip_bf16.h>
#include <stdint.h>

// Problem shape (fixed): inputs [4,2048,1024] f32, key [4096,1024] f32, value [4096,1024] f32
#define M_ROWS 8192   // B*L
#define D_DIM  1024
#define S_DIM  4096
#define DV_DIM 1024

typedef __attribute__((ext_vector_type(8))) short bf16x8;
typedef __attribute__((ext_vector_type(4))) float f32x4;
typedef unsigned short u16;

static __device__ __forceinline__ u16 f2bf(float x) {
  union { float f; unsigned u; } v; v.f = x;
  unsigned r = v.u + 0x7FFFu + ((v.u >> 16) & 1u);   // RNE
  return (u16)(r >> 16);
}
static __device__ __forceinline__ float bf2f(u16 h) {
  union { unsigned u; float f; } v; v.u = ((unsigned)h) << 16;
  return v.f;
}
// tanh-form gelu; |err vs exact erf-gelu| < ~1e-3, fine at this tolerance
static __device__ __forceinline__ float gelu_fast(float x) {
  float u = 0.7978845608028654f * x * (1.0f + 0.044715f * x * x);
  float e = __expf(2.0f * u);
  float t = 1.0f - 2.0f / (e + 1.0f);   // tanh(u)
  return 0.5f * x * (1.0f + t);
}

static __device__ __forceinline__ void gload16(const void* g, void* l) {
  __builtin_amdgcn_global_load_lds(
      (__attribute__((address_space(1))) void*)(void*)(g),
      (__attribute__((address_space(3))) void*)(l), 16, 0, 0);
}

// ---------------- cast f32 -> bf16 ----------------
__global__ __launch_bounds__(256)
void cast_f32_bf16(const float* __restrict__ in, u16* __restrict__ out, int n4) {
  const int i = blockIdx.x * 256 + threadIdx.x;
  if (i >= n4) return;
  const float4 v = ((const float4*)in)[i];
  ushort4 o;
  o.x = f2bf(v.x); o.y = f2bf(v.y); o.z = f2bf(v.z); o.w = f2bf(v.w);
  ((ushort4*)out)[i] = o;
}

// ------------- transpose + cast: V [R,C] f32 -> VT [C,R] bf16 -------------
__global__ __launch_bounds__(256)
void transpose_cast(const float* __restrict__ V, u16* __restrict__ VT, int R, int C) {
  __shared__ float tile[32][33];
  const int tx = threadIdx.x & 31;
  const int ty = threadIdx.x >> 5;
  const int r0 = blockIdx.y * 32;
  const int c0 = blockIdx.x * 32;
#pragma unroll
  for (int dy = 0; dy < 32; dy += 8)
    tile[ty + dy][tx] = V[(long)(r0 + ty + dy) * C + (c0 + tx)];
  __syncthreads();
#pragma unroll
  for (int dy = 0; dy < 32; dy += 8)
    VT[(long)(c0 + ty + dy) * R + (r0 + tx)] = f2bf(tile[tx][ty + dy]);
}

// ------------- scale[r] = 64 * rsqrt(sum_j Pp[r][j]) -------------
__global__ __launch_bounds__(256)
void finalize_scale(const float* __restrict__ Pp, float* __restrict__ scale,
                    int nBN, int rows) {
  const int r = blockIdx.x * 256 + threadIdx.x;
  if (r >= rows) return;
  float s = 0.f;
  for (int j = 0; j < nBN; ++j) s += Pp[(long)r * nBN + j];
  scale[r] = 64.0f * rsqrtf(s + 1e-30f);
}

// =================== 8-wave 256xBN GEMM: C = A[M,K] * Bm[N,K]^T ===================
// MODE 0 (BN=256, waves 2Mx4N): C = gelu(acc)->bf16, plus per-row ssq partials Pp[row][bn]
// MODE 1 (BN=128, waves 4Mx2N): C = acc*scale[row] -> f32
// BK=64, dbuf LDS, deep prefetch: A 1 tile ahead, B 2 tiles ahead (B(kt+2) overwrites
// B(kt)'s buffer AFTER READ_B consumed it into registers at phase 0). row&7 chunk swizzle.

#define VMW(N) asm volatile("s_waitcnt vmcnt(" #N ")" ::: "memory")

#define PH(P, STG, WT)                                                        \
  {                                                                           \
    bf16x8 af[MF][2];                                                         \
    _Pragma("unroll")                                                         \
    for (int j = 0; j < MF; ++j) {                                            \
      const int ar = wm * MSPAN + ((P) * MF + j) * 16 + fr;                   \
      af[j][0] = rdfrag(la, ar, 0);                                           \
      af[j][1] = rdfrag(la, ar, 1);                                           \
    }                                                                         \
    STG;                                                                      \
    __builtin_amdgcn_s_barrier();                                             \
    asm volatile("s_waitcnt lgkmcnt(0)" ::: "memory");                        \
    __builtin_amdgcn_sched_barrier(0);                                        \
    __builtin_amdgcn_s_setprio(1);                                            \
    _Pragma("unroll")                                                         \
    for (int j = 0; j < MF; ++j) {                                            \
      _Pragma("unroll")                                                       \
      for (int n = 0; n < NF; ++n) {                                          \
        acc[(P) * MF + j][n] = __builtin_amdgcn_mfma_f32_16x16x32_bf16(       \
            af[j][0], bfr[n][0], acc[(P) * MF + j][n], 0, 0, 0);              \
        acc[(P) * MF + j][n] = __builtin_amdgcn_mfma_f32_16x16x32_bf16(       \
            af[j][1], bfr[n][1], acc[(P) * MF + j][n], 0, 0, 0);              \
      }                                                                       \
    }                                                                         \
    __builtin_amdgcn_s_setprio(0);                                            \
    WT;                                                                       \
    __builtin_amdgcn_s_barrier();                                             \
  }

#define READ_B                                                                \
  {                                                                           \
    _Pragma("unroll")                                                         \
    for (int n = 0; n < NF; ++n) {                                            \
      const int br = wn * NSPAN + n * 16 + fr;                                \
      bfr[n][0] = rdfrag(lb, br, 0);                                          \
      bfr[n][1] = rdfrag(lb, br, 1);                                          \
    }                                                                         \
  }

// One K-tile: phases 0..3.  SAEN stages A(kt+1) in ph0/ph1, SBEN stages B(kt+2) in ph2(/ph3).
#define TILE(SAEN, SBEN, W1, W3)                                              \
  {                                                                           \
    const u16* la = ldsA[kt & 1];                                             \
    const u16* lb = ldsB[kt & 1];                                             \
    const int bA = (kt + 1) & 1;                                              \
    const int bB = kt & 1;                                                    \
    const long kA = (long)(kt + 1) * BK;                                      \
    const long kB = (long)(kt + 2) * BK;                                      \
    READ_B;                                                                   \
    if constexpr (BN == 256) {                                                \
      PH(0, if (SAEN) { SA(bA, 0, kA); SA(bA, 2, kA); }, {});                 \
      PH(1, if (SAEN) { SA(bA, 1, kA); SA(bA, 3, kA); }, W1);                 \
      PH(2, if (SBEN) { SB(bB, 0, kB); SB(bB, 1, kB); }, {});                 \
      PH(3, if (SBEN) { SB(bB, 2, kB); SB(bB, 3, kB); }, W3);                 \
    } else {                                                                  \
      PH(0, if (SAEN) { SA(bA, 0, kA); SA(bA, 1, kA); }, {});                 \
      PH(1, if (SAEN) { SA(bA, 2, kA); SA(bA, 3, kA); }, {});                 \
      PH(2, if (SBEN) { SB(bB, 0, kB); SB(bB, 1, kB); }, {});                 \
      PH(3, {}, W3);                                                          \
    }                                                                         \
  }

template <int MODE, int BN, int WM>
__global__ __launch_bounds__(512, 2)
void gemm8p(const u16* __restrict__ A, const u16* __restrict__ Bm,
            void* __restrict__ Cout, float* __restrict__ Pp,
            const float* __restrict__ scale,
            const int K, const int N, const int nBN, const int nWG) {
  constexpr int BM = 256, BK = 64;
  constexpr int WN = 8 / WM;
  constexpr int MSPAN = BM / WM;      // 128 (MODE0) / 64 (MODE1)
  constexpr int NSPAN = BN / WN;      // 64
  constexpr int MF = MSPAN / 64;      // frags per phase: 2 / 1
  constexpr int NF = NSPAN / 16;      // 4

  __shared__ u16 ldsA[2][BM * BK];
  __shared__ u16 ldsB[2][BN * BK];

  const int tid = threadIdx.x;
  const int lane = tid & 63;
  const int wv = tid >> 6;
  const int wm = wv / WN, wn = wv % WN;
  const int fr = lane & 15, hi = lane >> 4;

  // bijective XCD swizzle (m204)
  int wg;
  {
    const int q = nWG >> 3, r = nWG & 7;
    const int x = blockIdx.x & 7, ix = blockIdx.x >> 3;
    wg = (x < r ? x * (q + 1) : r * (q + 1) + (x - r) * q) + ix;
  }
  const int bm = wg / nBN, bn = wg % nBN;
  const long aR0 = (long)bm * BM;
  const long bR0 = (long)bn * BN;

  // staging: slot (row, s) holds global 16B-chunk s^(row&7)
  const int srow = tid >> 3;
  const int sch = (tid & 7) ^ (srow & 7);
  const long aoff = (aR0 + srow) * (long)K + sch * 8;
  const long boff = (bR0 + srow) * (long)K + sch * 8;

  auto SA = [&](int buf, int r, long kOff) {
    gload16(A + aoff + (long)r * 64 * K + kOff, &ldsA[buf][r * 4096 + tid * 8]);
  };
  auto SB = [&](int buf, int r, long kOff) {
    gload16(Bm + boff + (long)r * 64 * K + kOff, &ldsB[buf][r * 4096 + tid * 8]);
  };
  auto rdfrag = [&](const u16* base, int row, int kk) -> bf16x8 {
    return *(const bf16x8*)&base[row * 64 + (((kk << 2) | hi) ^ (row & 7)) * 8];
  };

  f32x4 acc[4 * MF][NF];
#pragma unroll
  for (int m = 0; m < 4 * MF; ++m)
#pragma unroll
    for (int n = 0; n < NF; ++n)
      acc[m][n] = f32x4{0.f, 0.f, 0.f, 0.f};

  bf16x8 bfr[NF][2];
  const int nK = K / BK;

  // ---- prologue: B(0), A(0), B(1); wait B(0)+A(0)-first-needed ----
  if constexpr (BN == 256) {
    SB(0, 0, 0); SB(0, 1, 0); SB(0, 2, 0); SB(0, 3, 0);
    SA(0, 0, 0); SA(0, 2, 0); SA(0, 1, 0); SA(0, 3, 0);
    SB(1, 0, BK); SB(1, 1, BK); SB(1, 2, BK); SB(1, 3, BK);
    VMW(6);   // retires B(0)x4 + A(0) rounds 0,2
  } else {
    SB(0, 0, 0); SB(0, 1, 0);
    SA(0, 0, 0); SA(0, 1, 0); SA(0, 2, 0); SA(0, 3, 0);
    SB(1, 0, BK); SB(1, 1, BK);
    VMW(2);   // retires B(0)x2 + A(0)x4
  }
  __builtin_amdgcn_s_barrier();

  int kt = 0;
  if constexpr (BN == 256) {
    for (; kt < nK - 2; ++kt) TILE(true, true, VMW(8), VMW(6));
    TILE(true, false, VMW(8), VMW(2)); ++kt;
    TILE(false, false, VMW(0), {});
  } else {
    for (; kt < nK - 2; ++kt) TILE(true, true, {}, VMW(2));
    TILE(true, false, {}, VMW(0)); ++kt;
    TILE(false, false, {}, {});
  }

  // ---- epilogue; C/D: col=fr, row=hi*4+i ----
  if constexpr (MODE == 0) {
    u16* Cg = (u16*)Cout;
    float* red = (float*)&ldsA[0][0];   // [BM][WN] f32 = 4 KB, safe after final barrier
#pragma unroll
    for (int m = 0; m < 4 * MF; ++m) {
#pragma unroll
      for (int i = 0; i < 4; ++i) {
        const int rl = wm * MSPAN + m * 16 + hi * 4 + i;
        const long r = aR0 + rl;
        float s = 0.f;
#pragma unroll
        for (int n = 0; n < NF; ++n) {
          const float g = gelu_fast(acc[m][n][i]);
          Cg[r * N + bR0 + wn * NSPAN + n * 16 + fr] = f2bf(g);
          s += g * g;
        }
        s += __shfl_xor(s, 1); s += __shfl_xor(s, 2);
        s += __shfl_xor(s, 4); s += __shfl_xor(s, 8);
        if (fr == 0) red[rl * WN + wn] = s;
      }
    }
    __syncthreads();
    if (tid < BM) {
      float s = 0.f;
#pragma unroll
      for (int w = 0; w < WN; ++w) s += red[tid * WN + w];
      Pp[(aR0 + tid) * nBN + bn] = s;
    }
  } else {
    float* Cf = (float*)Cout;
#pragma unroll
    for (int m = 0; m < 4 * MF; ++m) {
#pragma unroll
      for (int i = 0; i < 4; ++i) {
        const long r = aR0 + wm * MSPAN + m * 16 + hi * 4 + i;
        const float s = scale[r];
#pragma unroll
        for (int n = 0; n < NF; ++n)
          Cf[r * N + bR0 + wn * NSPAN + n * 16 + fr] = acc[m][n][i] * s;
      }
    }
  }
}

extern "C" void kernel_launch(void* const* d_in, const int* in_sizes, int n_in,
                              void* d_out, int out_size, void* d_ws, size_t ws_size,
                              hipStream_t stream) {
  const float* Qf = (const float*)d_in[0];
  const float* Kf = (const float*)d_in[1];
  const float* Vf = (const float*)d_in[2];
  float* Out = (float*)d_out;

  const int M = M_ROWS, D = D_DIM, S = S_DIM, DV = DV_DIM;
  const int nBN1 = S / 256;    // 16
  const int nBN2 = DV / 128;   // 8

  // workspace layout
  char* p = (char*)d_ws;
  u16* Qb = (u16*)p;            p += (size_t)M * D * 2;        // 16 MB
  u16* Kb = (u16*)p;            p += (size_t)S * D * 2;        //  8 MB
  u16* VT = (u16*)p;            p += (size_t)DV * S * 2;       //  8 MB
  float* scalebuf = (float*)p;  p += (size_t)M * 4;            // 32 KB
  float* Pp = (float*)p;        p += (size_t)M * nBN1 * 4;     // 512 KB
  u16* G = (u16*)p;                                            // up to 64 MB
  const size_t fixed = (size_t)(p - (char*)d_ws);
  const size_t avail = (ws_size > fixed) ? (ws_size - fixed) : 0;

  // M-chunking (multiples of 256) so the G panel fits
  const size_t bytes_per_row = (size_t)S * 2;
  size_t rows_fit = avail / bytes_per_row;
  int chunk = (int)((rows_fit / 256) * 256);
  if (chunk > M) chunk = M;
  if (chunk < 256) chunk = 256;

  cast_f32_bf16<<<(M * D / 4 + 255) / 256, 256, 0, stream>>>(Qf, Qb, M * D / 4);
  cast_f32_bf16<<<(S * D / 4 + 255) / 256, 256, 0, stream>>>(Kf, Kb, S * D / 4);
  transpose_cast<<<dim3(DV / 32, S / 32), 256, 0, stream>>>(Vf, VT, S, DV);

  for (int m0 = 0; m0 < M; m0 += chunk) {
    const int rows = (M - m0 < chunk) ? (M - m0) : chunk;
    const int nWG1 = (rows / 256) * nBN1;
    gemm8p<0, 256, 2><<<dim3(nWG1), 512, 0, stream>>>(
        Qb + (size_t)m0 * D, Kb, (void*)G, Pp, nullptr, D, S, nBN1, nWG1);
    finalize_scale<<<(rows + 255) / 256, 256, 0, stream>>>(Pp, scalebuf, nBN1, rows);
    const int nWG2 = (rows / 256) * nBN2;
    gemm8p<1, 128, 4><<<dim3(nWG2), 512, 0, stream>>>(
        G, VT, (void*)(Out + (size_t)m0 * DV), nullptr, scalebuf, S, DV, nBN2, nWG2);
  }
}